// Round 4
// baseline (565.571 us; speedup 1.0000x reference)
//
#include <hip/hip_runtime.h>

// Problem constants (from reference):
//   obj   : [1, 2048, 2048] fp32      (in_sizes[0] = 4,194,304)
//   waves : [4, 1024, 128, 128] fp32  (in_sizes[1] = 67,108,864)
//   pos   : [1024, 2] int32           (in_sizes[2] = 2,048), values in [0,1920)
// Outputs (concatenated in d_out, fp32):
//   patches     : [1024, 1, 128, 128] = 16,777,216 elems
//   object_norm : [2048, 2048]        =  4,194,304 elems
//
// R4 = R3 with the nontemporal builtins fixed (clang requires ext_vector_type,
// not HIP_vector_type). Theory unchanged:
//
// Single-pass scatter. R2 post-mortem: the tile-gather is L3-line-BW bound
// (~460-600 MB of 128B-line traffic regardless of tile size). Mandatory
// traffic is only ~400 MB: read waves once (coalesced), read obj
// (L3-friendly), write patches, write norm. Achieve it by computing
// patch_norm in registers during the streaming waves pass and scatter-adding
// into norm with coalesced device-scope f32 atomics (16.7M lane-atomics,
// avg 4-way multiplicity, 16 MB target -> cache-side). No tile lists, no
// second pass, no pnorm round-trip.

#define NMODES 4
#define NB     1024
#define PH     128
#define PW     128
#define OH     2048
#define OW     2048

typedef float vfloat4 __attribute__((ext_vector_type(4)));

// ---------------------------------------------------------------------------
// Fused kernel: crop + 4-mode reduce + scatter-add.
// One thread per aligned quad of 4 consecutive w elements; 16 blocks/batch,
// so pos reads are wave-uniform (scalar loads).
// ---------------------------------------------------------------------------
__global__ __launch_bounds__(256) void crop_reduce_scatter(
    const float* __restrict__ obj,
    const float* __restrict__ waves,
    const int*   __restrict__ pos,
    float* __restrict__ patches,
    float* __restrict__ norm)
{
    const int q     = blockIdx.x * blockDim.x + threadIdx.x;
    const int b     = q >> 12;          // quads per batch = PH*PW/4 = 4096
    const int local = q & 4095;
    const int h     = local >> 5;       // 32 quads per row
    const int w     = (local & 31) << 2;

    const int r0 = pos[b * 2 + 0];      // uniform per block -> s_load
    const int c0 = pos[b * 2 + 1];

    // --- crop: patches[b,h,w..w+3] = obj[r0+h, c0+w..w+3] (unaligned src) ---
    const int oidx = (r0 + h) * OW + (c0 + w);
    vfloat4 p;
    p.x = obj[oidx + 0];
    p.y = obj[oidx + 1];
    p.z = obj[oidx + 2];
    p.w = obj[oidx + 3];
    const int pbase = b * (PH * PW) + h * PW + w;   // 16B-aligned
    __builtin_nontemporal_store(p, reinterpret_cast<vfloat4*>(patches + pbase));

    // --- mode reduce in registers: s = sum_m waves[m,b,h,w..w+3]^2 ---
    const int MS = NB * PH * PW;        // mode stride in elements
    const vfloat4 w0 = __builtin_nontemporal_load(
        reinterpret_cast<const vfloat4*>(waves + pbase));
    const vfloat4 w1 = __builtin_nontemporal_load(
        reinterpret_cast<const vfloat4*>(waves + MS + pbase));
    const vfloat4 w2 = __builtin_nontemporal_load(
        reinterpret_cast<const vfloat4*>(waves + 2 * MS + pbase));
    const vfloat4 w3 = __builtin_nontemporal_load(
        reinterpret_cast<const vfloat4*>(waves + 3 * MS + pbase));

    const vfloat4 s = w0 * w0 + w1 * w1 + w2 * w2 + w3 * w3;

    // --- scatter: norm[r0+h, c0+w..w+3] += s (coalesced, device-scope) ---
    atomicAdd(&norm[oidx + 0], s.x);
    atomicAdd(&norm[oidx + 1], s.y);
    atomicAdd(&norm[oidx + 2], s.z);
    atomicAdd(&norm[oidx + 3], s.w);
}

extern "C" void kernel_launch(void* const* d_in, const int* in_sizes, int n_in,
                              void* d_out, int out_size, void* d_ws, size_t ws_size,
                              hipStream_t stream) {
    const float* obj   = (const float*)d_in[0];
    const float* waves = (const float*)d_in[1];
    const int*   pos   = (const int*)d_in[2];

    float* patches = (float*)d_out;                        // 16,777,216 elems
    float* norm    = (float*)d_out + (size_t)NB * PH * PW; // 4,194,304 elems

    // norm is accumulated via atomics -> must start at zero (d_out poisoned).
    // 16 MB fill at ~6.5 TB/s ~ 2.6 us, stream-ordered before the kernel.
    (void)hipMemsetAsync(norm, 0, (size_t)OH * OW * sizeof(float), stream);

    const int quads = NB * PH * PW / 4;  // 4,194,304
    crop_reduce_scatter<<<quads / 256, 256, 0, stream>>>(obj, waves, pos,
                                                         patches, norm);
}

// Round 5
// 416.248 us; speedup vs baseline: 1.3587x; 1.3587x over previous
//
#include <hip/hip_runtime.h>

// Problem constants (from reference):
//   obj   : [1, 2048, 2048] fp32      (16 MB, L3-resident)
//   waves : [4, 1024, 128, 128] fp32  (256 MB)
//   pos   : [1024, 2] int32           values in [0,1920)
// Outputs (concatenated in d_out, fp32):
//   patches     : [1024, 1, 128, 128]
//   object_norm : [2048, 2048]
//
// R5: back to the R0 gather structure (R4 post-mortem: scatter atomics run
// memory-side RMW, 260us, WRITE_SIZE 335MB -- dead end). Attack the gather's
// two measured costs:
//  1. 128B-line straddle waste: TS 64->128 cuts segments/patch-row ~3->2,
//     line traffic ~424 -> ~356 MB.
//  2. Issued-iteration overhead: pairs 9216 -> ~4060, plus a (uniform in
//     practice) row-range early-out that skips ~47% of (entry,slice) pairs.

#define NMODES 4
#define NB     1024
#define PH     128
#define PW     128
#define OH     2048
#define OW     2048

#define TS       128             // object tile size (128x128)
#define NT_X     (OW / TS)       // 16
#define NT_Y     (OH / TS)       // 16
#define NT       (NT_X * NT_Y)   // 256 tiles
#define CAP      64              // batches per tile: mean ~18, P(>64) ~ 0
#define SLICES   16              // 128x8 row-slices -> 4096 blocks
#define SH       (TS / SLICES)   // 8 rows per slice

// ---------------------------------------------------------------------------
// Kernel A: patch crop (gather from obj, L3-resident) + batch->tile binning.
// One thread per aligned quad of 4 consecutive w elements.
// ---------------------------------------------------------------------------
__global__ __launch_bounds__(256) void crop_and_bin(
    const float* __restrict__ obj,
    const int*   __restrict__ pos,
    float* __restrict__ patches,
    int*   __restrict__ tile_cnt,
    int*   __restrict__ tile_list)
{
    const int q = blockIdx.x * blockDim.x + threadIdx.x;

    // --- binning (first NB threads only; <=4 tiny int atomics each) ---
    if (q < NB) {
        const int r0 = pos[2 * q];
        const int c0 = pos[2 * q + 1];
        const int ty0 = r0 >> 7, ty1 = (r0 + PH - 1) >> 7;
        const int tx0 = c0 >> 7, tx1 = (c0 + PW - 1) >> 7;
        for (int ty = ty0; ty <= ty1; ++ty)
            for (int tx = tx0; tx <= tx1; ++tx) {
                const int t = ty * NT_X + tx;
                const int idx = atomicAdd(&tile_cnt[t], 1);
                if (idx < CAP) tile_list[t * CAP + idx] = q;
            }
    }

    // --- crop: patches[b,h,w..w+3] = obj[r0+h, c0+w..w+3] ---
    const int b     = q >> 12;          // quads per batch = PH*PW/4 = 4096
    const int local = q & 4095;
    const int h     = local >> 5;       // 32 quads per row
    const int w     = (local & 31) << 2;

    const int r0 = pos[b * 2 + 0];
    const int c0 = pos[b * 2 + 1];

    const int oidx = (r0 + h) * OW + (c0 + w);
    float4 p;
    p.x = obj[oidx + 0];
    p.y = obj[oidx + 1];
    p.z = obj[oidx + 2];
    p.w = obj[oidx + 3];
    *reinterpret_cast<float4*>(patches + b * (PH * PW) + h * PW + w) = p;
}

// ---------------------------------------------------------------------------
// Kernel B: object_norm via gather. 4096 blocks = 256 tiles x 16 row-slices
// (128 wide x 8 tall). 256 threads/block; each thread owns 4 pixels (same x,
// rows phase+{0,2,4,6}). Per entry: uniform row-range early-out, then
// branchless clamped loads (always legal, mostly coalesced), masked adds.
// ---------------------------------------------------------------------------
__global__ __launch_bounds__(256) void norm_gather(
    const float* __restrict__ waves,
    const int*   __restrict__ pos,
    const int*   __restrict__ tile_cnt,
    const int*   __restrict__ tile_list,
    float* __restrict__ norm)
{
    const int blk = blockIdx.x;
    const int t   = blk >> 4;           // tile id (0..255)
    const int s   = blk & 15;           // row-slice within tile
    const int Y0  = (t >> 4) * TS + s * SH;
    const int X0  = (t & 15) * TS;

    __shared__ int s_base[CAP];         // b * PH*PW
    __shared__ int s_r[CAP];
    __shared__ int s_c[CAP];

    const int count = min(tile_cnt[t], CAP);
    for (int i = threadIdx.x; i < count; i += 256) {
        const int b = tile_list[t * CAP + i];
        s_base[i] = b * (PH * PW);
        s_r[i]    = pos[2 * b];
        s_c[i]    = pos[2 * b + 1];
    }
    __syncthreads();

    const int x     = threadIdx.x & 127; // 128 lanes span one tile row
    const int phase = threadIdx.x >> 7;  // 0..1
    const int X     = X0 + x;
    const int Y     = Y0 + phase;        // rows Y, Y+2, Y+4, Y+6

    const int MS = NB * PH * PW;         // mode stride in elements

    float acc0 = 0.0f, acc1 = 0.0f, acc2 = 0.0f, acc3 = 0.0f;

    for (int i = 0; i < count; ++i) {
        const int r0 = s_r[i];           // broadcast LDS reads (conflict-free)
        // Uniform-in-practice early-out: patch rows [r0, r0+PH) vs slice
        // rows [Y0, Y0+SH). Skips ~47% of entries with one s_cbranch.
        if (r0 >= Y0 + SH || r0 + PH <= Y0) continue;

        const int c0 = s_c[i];
        const int bb = s_base[i];

        const int dc  = X - c0;
        const bool vc = (unsigned)dc < (unsigned)PW;
        const int dcc = min(max(dc, 0), PW - 1);
        const float* wp = waves + bb + dcc;

        const int dr0 = Y     - r0;
        const int dr1 = dr0 + 2;
        const int dr2 = dr0 + 4;
        const int dr3 = dr0 + 6;

        const bool v0 = vc & ((unsigned)dr0 < (unsigned)PH);
        const bool v1 = vc & ((unsigned)dr1 < (unsigned)PH);
        const bool v2 = vc & ((unsigned)dr2 < (unsigned)PH);
        const bool v3 = vc & ((unsigned)dr3 < (unsigned)PH);

        const int o0 = min(max(dr0, 0), PH - 1) * PW;
        const int o1 = min(max(dr1, 0), PH - 1) * PW;
        const int o2 = min(max(dr2, 0), PH - 1) * PW;
        const int o3 = min(max(dr3, 0), PH - 1) * PW;

        // 16 independent loads -> deep MLP; mostly L2/L3 hits
        const float a0 = wp[o0], a1 = wp[o0 + MS], a2 = wp[o0 + 2 * MS], a3 = wp[o0 + 3 * MS];
        const float b0 = wp[o1], b1 = wp[o1 + MS], b2 = wp[o1 + 2 * MS], b3 = wp[o1 + 3 * MS];
        const float e0 = wp[o2], e1 = wp[o2 + MS], e2 = wp[o2 + 2 * MS], e3 = wp[o2 + 3 * MS];
        const float d0 = wp[o3], d1 = wp[o3 + MS], d2 = wp[o3 + 2 * MS], d3 = wp[o3 + 3 * MS];

        const float s0 = a0 * a0 + a1 * a1 + a2 * a2 + a3 * a3;
        const float s1 = b0 * b0 + b1 * b1 + b2 * b2 + b3 * b3;
        const float s2 = e0 * e0 + e1 * e1 + e2 * e2 + e3 * e3;
        const float s3 = d0 * d0 + d1 * d1 + d2 * d2 + d3 * d3;

        acc0 += v0 ? s0 : 0.0f;          // v_cndmask + v_add (no branch)
        acc1 += v1 ? s1 : 0.0f;
        acc2 += v2 ? s2 : 0.0f;
        acc3 += v3 ? s3 : 0.0f;
    }

    norm[(Y    ) * OW + X] = acc0;       // every pixel written exactly once
    norm[(Y + 2) * OW + X] = acc1;
    norm[(Y + 4) * OW + X] = acc2;
    norm[(Y + 6) * OW + X] = acc3;
}

extern "C" void kernel_launch(void* const* d_in, const int* in_sizes, int n_in,
                              void* d_out, int out_size, void* d_ws, size_t ws_size,
                              hipStream_t stream) {
    const float* obj   = (const float*)d_in[0];
    const float* waves = (const float*)d_in[1];
    const int*   pos   = (const int*)d_in[2];

    float* patches = (float*)d_out;                        // 16,777,216 elems
    float* norm    = (float*)d_out + (size_t)NB * PH * PW; // 4,194,304 elems

    // Workspace layout: [tile_cnt: NT ints][tile_list: NT*CAP ints] = 65 KB
    int* tile_cnt  = (int*)d_ws;
    int* tile_list = tile_cnt + NT;

    // ws is poisoned each call -> zero the counters (1 KB, async).
    (void)hipMemsetAsync(tile_cnt, 0, NT * sizeof(int), stream);

    const int quads = NB * PH * PW / 4;  // 4,194,304
    crop_and_bin<<<quads / 256, 256, 0, stream>>>(obj, pos, patches,
                                                  tile_cnt, tile_list);
    // Stream order guarantees tile lists are complete & visible device-wide.
    norm_gather<<<NT * SLICES, 256, 0, stream>>>(waves, pos, tile_cnt,
                                                 tile_list, norm);
}

// Round 6
// 403.390 us; speedup vs baseline: 1.4020x; 1.0319x over previous
//
#include <hip/hip_runtime.h>

// Problem constants (from reference):
//   obj   : [1, 2048, 2048] fp32      (16 MB, L3-resident)
//   waves : [4, 1024, 128, 128] fp32  (256 MB)
//   pos   : [1024, 2] int32           values in [0,1920)
// Outputs (concatenated in d_out, fp32):
//   patches     : [1024, 1, 128, 128]
//   object_norm : [2048, 2048]
//
// R6: single-launch fusion. R5 post-mortem: tile-size moves (32/128) around
// TS=64 are neutral-to-worse -> gather is near its local optimum; remaining
// slack is the SERIALIZATION of crop (obj->patches stream) and gather
// (waves->norm stream) plus launch/memset overhead. Fix: the gather blocks
// rebuild their own per-slice batch lists by scanning pos (8 KB, L2-hot,
// 4 iterations/block) into LDS -> no tile-list dependency, no workspace,
// no memset, ONE kernel. Gather and crop blocks interleaved 2:1 in the grid
// so both memory streams run concurrently. Per-slice binning also subsumes
// R5's row early-out exactly (only intersecting entries are listed).
// patches/norm stores are nontemporal (never re-read) to preserve L2/L3
// for the gathered waves lines.

#define NMODES 4
#define NB     1024
#define PH     128
#define PW     128
#define OH     2048
#define OW     2048

#define TS       64              // object tile size (64x64) -- measured best
#define NT_X     (OW / TS)       // 32
#define NT_Y     (OH / TS)       // 32
#define SLICES   8               // 64x8 row-slices per tile
#define SH       (TS / SLICES)   // 8 rows per slice
#define NGATHER  (NT_X * NT_Y * SLICES)   // 8192 gather blocks
#define NCROP    (NB * PH * PW / 4 / 256) // 16384 crop blocks
#define NTOTAL   (NGATHER + NCROP)        // 24576
#define CAP      48              // per-slice entries: mean ~7.3, P(>48) ~ 0

typedef float vfloat4 __attribute__((ext_vector_type(4)));

// ---------------------------------------------------------------------------
// Fused kernel. bid % 3 == 0 -> gather block (8192 of them, ids 0..8191);
// otherwise crop block (16384 of them). The 2:1 interleave keeps the
// obj/patches stream and the waves/norm stream concurrently active across
// the whole dispatch.
// ---------------------------------------------------------------------------
__global__ __launch_bounds__(256) void fused_crop_norm(
    const float* __restrict__ obj,
    const float* __restrict__ waves,
    const int*   __restrict__ pos,
    float* __restrict__ patches,
    float* __restrict__ norm)
{
    const int bid = blockIdx.x;
    const int tid = threadIdx.x;

    __shared__ int s_cnt;
    __shared__ int s_base[CAP];
    __shared__ int s_r[CAP];
    __shared__ int s_c[CAP];

    if (bid % 3 == 0) {
        // =================== gather: one 64x8 slice of norm ===============
        const int g  = bid / 3;            // 0..8191
        const int t  = g >> 3;             // tile id 0..1023
        const int s  = g & 7;              // row-slice within tile
        const int Y0 = (t >> 5) * TS + s * SH;
        const int X0 = (t & 31) * TS;

        // --- self-binning: scan pos (8 KB, L2-hot), append hits to LDS ---
        if (tid == 0) s_cnt = 0;
        __syncthreads();
        for (int b = tid; b < NB; b += 256) {
            const int r0 = pos[2 * b];
            const int c0 = pos[2 * b + 1];
            const bool hit = (r0 < Y0 + SH) & (r0 + PH > Y0) &
                             (c0 < X0 + TS) & (c0 + PW > X0);
            if (hit) {
                const int i = atomicAdd(&s_cnt, 1);
                if (i < CAP) {
                    s_base[i] = b * (PH * PW);
                    s_r[i]    = r0;
                    s_c[i]    = c0;
                }
            }
        }
        __syncthreads();
        const int count = min(s_cnt, CAP);

        const int x     = tid & 63;        // 64 lanes span one slice row
        const int phase = tid >> 6;        // 0..3
        const int X     = X0 + x;
        const int Ya    = Y0 + phase;      // first owned row
        const int Yb    = Ya + 4;          // second owned row

        const int MS = NB * PH * PW;       // mode stride in elements

        float acc_a = 0.0f;
        float acc_b = 0.0f;

        #pragma unroll 2
        for (int i = 0; i < count; ++i) {
            const int r0 = s_r[i];         // broadcast LDS reads
            const int c0 = s_c[i];
            const int bb = s_base[i];

            const int dra = Ya - r0;
            const int drb = Yb - r0;
            const int dc  = X  - c0;

            const bool vc = (unsigned)dc < (unsigned)PW;
            const bool va = vc & ((unsigned)dra < (unsigned)PH);
            const bool vb = vc & ((unsigned)drb < (unsigned)PH);

            // clamp into the patch -> loads always legal, mostly coalesced
            const int dcc  = min(max(dc, 0),  PW - 1);
            const int drac = min(max(dra, 0), PH - 1);
            const int drbc = min(max(drb, 0), PH - 1);

            const float* wa = waves + bb + drac * PW + dcc;
            const float* wb = waves + bb + drbc * PW + dcc;

            const float a0 = wa[0];
            const float a1 = wa[MS];
            const float a2 = wa[2 * MS];
            const float a3 = wa[3 * MS];
            const float b0 = wb[0];
            const float b1 = wb[MS];
            const float b2 = wb[2 * MS];
            const float b3 = wb[3 * MS];

            const float sa = a0 * a0 + a1 * a1 + a2 * a2 + a3 * a3;
            const float sb = b0 * b0 + b1 * b1 + b2 * b2 + b3 * b3;
            acc_a += va ? sa : 0.0f;       // v_cndmask + v_add (no branch)
            acc_b += vb ? sb : 0.0f;
        }

        // every pixel written exactly once; never re-read -> nontemporal
        __builtin_nontemporal_store(acc_a, norm + Ya * OW + X);
        __builtin_nontemporal_store(acc_b, norm + Yb * OW + X);
    } else {
        // =================== crop: one 256-quad chunk of patches ==========
        const int c     = bid - bid / 3 - 1;   // 0..16383
        const int q     = c * 256 + tid;
        const int b     = q >> 12;             // quads/batch = PH*PW/4
        const int local = q & 4095;
        const int h     = local >> 5;          // 32 quads per row
        const int w     = (local & 31) << 2;

        const int r0 = pos[b * 2 + 0];         // wave-uniform -> s_load
        const int c0 = pos[b * 2 + 1];

        const int oidx = (r0 + h) * OW + (c0 + w);
        vfloat4 p;
        p.x = obj[oidx + 0];
        p.y = obj[oidx + 1];
        p.z = obj[oidx + 2];
        p.w = obj[oidx + 3];
        // patches never re-read -> nontemporal 16B store
        __builtin_nontemporal_store(
            p, reinterpret_cast<vfloat4*>(patches + b * (PH * PW) + h * PW + w));
    }
}

extern "C" void kernel_launch(void* const* d_in, const int* in_sizes, int n_in,
                              void* d_out, int out_size, void* d_ws, size_t ws_size,
                              hipStream_t stream) {
    const float* obj   = (const float*)d_in[0];
    const float* waves = (const float*)d_in[1];
    const int*   pos   = (const int*)d_in[2];

    float* patches = (float*)d_out;                        // 16,777,216 elems
    float* norm    = (float*)d_out + (size_t)NB * PH * PW; // 4,194,304 elems

    // No workspace, no memset, one launch.
    fused_crop_norm<<<NTOTAL, 256, 0, stream>>>(obj, waves, pos,
                                                patches, norm);
}